// Round 1
// baseline (184.197 us; speedup 1.0000x reference)
//
#include <hip/hip_runtime.h>

// Problem constants (from reference):
#define B_  4
#define C_  64
#define H_  192
#define W_  640
#define D_  96          // NUM_DISP
#define KC  16          // channel chunk staged in LDS
#define TW  64          // w-tile per block
#define RW  160         // R tile width: 159 needed (w0-95 .. w0+63), padded to 160

// Each block: one (b,h), one 64-wide w tile, all 96 disparities.
// 256 threads = 16 d-groups (6 d each) x 16 w-groups (4 w each).
// out[((b*D + d)*H + h)*W + w] = sum_c L[b,c,h,w] * R[b,c,h,(w - d*S) mod W]
template <int S>
__global__ __launch_bounds__(256)
void cost_volume_kernel(const float* __restrict__ Lp,
                        const float* __restrict__ Rp,
                        const int* __restrict__ dirp,
                        float* __restrict__ out)
{
    // self-select the matching direction instantiation (uniform branch)
    if (dirp[0] != S) return;

    __shared__ float Ls[KC][TW];
    __shared__ float Rs[KC][RW];

    const int wt = blockIdx.x;          // 0..9
    const int bh = blockIdx.y;          // 0..767
    const int b  = bh / H_;
    const int h  = bh % H_;
    const int w0 = wt * TW;

    const int tid = threadIdx.x;
    const int tw  = tid & 15;           // w-group: w = w0 + tw*4 + j
    const int td  = tid >> 4;           // d-group: d = td*6 + i

    // R columns needed: w0 + [0,63] - S*[0,95]
    //  S=+1 -> [w0-95, w0+63], base = w0-95, k = (w - w0) + 95 - d
    //  S=-1 -> [w0,    w0+158], base = w0,    k = (w - w0) + d
    const int base = (S == 1) ? (w0 - 95) : w0;

    const float* Lrow = Lp + ((size_t)b * C_ * H_ + h) * W_;  // + c*H*W later
    const float* Rrow = Rp + ((size_t)b * C_ * H_ + h) * W_;

    float acc[6][4];
#pragma unroll
    for (int i = 0; i < 6; ++i)
#pragma unroll
        for (int j = 0; j < 4; ++j) acc[i][j] = 0.f;

    for (int c0 = 0; c0 < C_; c0 += KC) {
        // ---- stage L tile: KC*TW = 1024 floats, 4 per thread, coalesced ----
#pragma unroll
        for (int x = 0; x < (KC * TW) / 256; ++x) {
            const int idx = tid + x * 256;
            const int cc  = idx >> 6;          // /64
            const int dw  = idx & 63;
            Ls[cc][dw] = Lrow[(size_t)(c0 + cc) * H_ * W_ + w0 + dw];
        }
        // ---- stage R tile: KC*RW = 2560 floats, 10 per thread ----
#pragma unroll
        for (int x = 0; x < (KC * RW) / 256; ++x) {
            const int idx = tid + x * 256;
            const int cc  = idx / RW;
            const int k   = idx % RW;
            int col = base + k;                // in [-95, W+158]
            if (col < 0)   col += W_;
            if (col >= W_) col -= W_;
            Rs[cc][k] = Rrow[(size_t)(c0 + cc) * H_ * W_ + col];
        }
        __syncthreads();

        // ---- compute: per channel, 4 L values + 9 contiguous R values -> 24 MACs
#pragma unroll
        for (int cc = 0; cc < KC; ++cc) {
            const float4 Lv4 = *reinterpret_cast<const float4*>(&Ls[cc][tw * 4]);
            const float Lv[4] = {Lv4.x, Lv4.y, Lv4.z, Lv4.w};

            // k(w=w0+tw*4+j, d=td*6+i) = kbase + r, r in [0,8]
            //  S=+1: kbase = tw*4 - td*6 + 90, r = j + 5 - i
            //  S=-1: kbase = tw*4 + td*6,      r = j + i
            const int kbase = (S == 1) ? (tw * 4 - td * 6 + 90)
                                       : (tw * 4 + td * 6);
            float Rv[9];
#pragma unroll
            for (int r = 0; r < 9; ++r) Rv[r] = Rs[cc][kbase + r];

#pragma unroll
            for (int i = 0; i < 6; ++i) {
#pragma unroll
                for (int j = 0; j < 4; ++j) {
                    const int r = (S == 1) ? (j + 5 - i) : (j + i);
                    acc[i][j] += Lv[j] * Rv[r];
                }
            }
        }
        __syncthreads();
    }

    // ---- write out: d = td*6+i, w = w0 + tw*4 + j, float4 coalesced ----
    float* orow = out + ((size_t)b * D_ * H_ + h) * W_ + w0 + tw * 4;
#pragma unroll
    for (int i = 0; i < 6; ++i) {
        const int d = td * 6 + i;
        float4 v = make_float4(acc[i][0], acc[i][1], acc[i][2], acc[i][3]);
        *reinterpret_cast<float4*>(orow + (size_t)d * H_ * W_) = v;
    }
}

extern "C" void kernel_launch(void* const* d_in, const int* in_sizes, int n_in,
                              void* d_out, int out_size, void* d_ws, size_t ws_size,
                              hipStream_t stream)
{
    const float* un_l = (const float*)d_in[0];
    const float* un_r = (const float*)d_in[1];
    const int*   dirp = (const int*)d_in[2];
    float* out = (float*)d_out;

    dim3 grid(W_ / TW, B_ * H_);   // (10, 768)
    dim3 block(256);

    // Launch both direction instantiations; the mismatching one exits
    // immediately after a uniform load (direction is only known on device).
    cost_volume_kernel<1><<<grid, block, 0, stream>>>(un_l, un_r, dirp, out);
    cost_volume_kernel<-1><<<grid, block, 0, stream>>>(un_l, un_r, dirp, out);
}

// Round 2
// 108.446 us; speedup vs baseline: 1.6985x; 1.6985x over previous
//
#include <hip/hip_runtime.h>

// Problem constants
#define B_   4
#define C_   64
#define H_   192
#define W_   640
#define D_   96     // disparities
#define TWB  64     // w1 columns per block
#define RWID 160    // staged R columns (band w0-96 .. w0+63 or w0 .. w0+159)
#define NDL  7      // 16-wide delta tiles covering d in [0,96)

typedef __attribute__((ext_vector_type(8))) short short8;
typedef __attribute__((ext_vector_type(4))) float float4v;

// f32 -> bf16 round-to-nearest-even
__device__ inline unsigned short f2b(float f) {
    unsigned int u = __builtin_bit_cast(unsigned int, f);
    u += 0x7FFFu + ((u >> 16) & 1u);
    return (unsigned short)(u >> 16);
}

// out[b,0,d,h,w] = sum_c L[b,c,h,w] * R[b,c,h,(w - d*S) mod W]
//               = G[w][w - S*d],  G[w1][w2] = sum_c L[c,w1] R[c,w2]
template <int S>
__global__ __launch_bounds__(256)
void cost_volume_mfma(const float* __restrict__ Lp,
                      const float* __restrict__ Rp,
                      const int* __restrict__ dirp,
                      float* __restrict__ out)
{
    // self-select direction instantiation (uniform exit)
    if (dirp[0] != S) return;

    __shared__ unsigned short Lb[TWB * C_];    //  8 KB, [w][c] bf16, XOR-swizzled
    __shared__ unsigned short Rb[RWID * C_];   // 20 KB, [k][c] bf16, XOR-swizzled
    __shared__ float Gs[TWB * 97];             // 24.8 KB, [w_local][d], pad to 97

    // XCD-chunked bijective swizzle: nwg = 7680 = 8 * 960.
    // XCD x gets a contiguous run of (b,h) rows -> R band reuse in its L2.
    const int orig = blockIdx.x;
    const int nid  = (orig & 7) * 960 + (orig >> 3);
    const int bh   = nid / 10;          // (b,h) row
    const int t1g  = nid % 10;          // which 64-wide w slab
    const int b  = bh / H_;
    const int h  = bh % H_;
    const int w0 = t1g * TWB;
    const int rbase = (S == 1) ? (w0 - 96) : w0;  // global col of Rb[k=0]

    const int tid = threadIdx.x;
    const float* Lrow = Lp + ((size_t)b * C_ * H_ + h) * W_;
    const float* Rrow = Rp + ((size_t)b * C_ * H_ + h) * W_;

    unsigned int* Lw = (unsigned int*)Lb;
    unsigned int* Rw = (unsigned int*)Rb;

    // ---- stage L: units = 32 cpair x 16 w4 = 512, 2 per thread ----
#pragma unroll
    for (int u0 = 0; u0 < 2; ++u0) {
        const int u  = tid + u0 * 256;
        const int cp = u >> 4;          // 0..31
        const int w4 = u & 15;          // 0..15
        const int c  = cp * 2;
        const float4 a = *(const float4*)(Lrow + (size_t)c     * H_ * W_ + w0 + w4 * 4);
        const float4 q = *(const float4*)(Lrow + (size_t)(c+1) * H_ * W_ + w0 + w4 * 4);
        const float av[4] = {a.x, a.y, a.z, a.w};
        const float qv[4] = {q.x, q.y, q.z, q.w};
#pragma unroll
        for (int i = 0; i < 4; ++i) {
            const int w = w4 * 4 + i;
            const unsigned int val =
                (unsigned int)f2b(av[i]) | ((unsigned int)f2b(qv[i]) << 16);
            Lw[(w * 64 + (c ^ ((w & 7) << 3))) >> 1] = val;
        }
    }

    // ---- stage R: units = 32 cpair x 160 k = 5120, 20 per thread ----
#pragma unroll 4
    for (int u0 = 0; u0 < 20; ++u0) {
        const int u  = tid + u0 * 256;
        const int cp = u / RWID;
        const int kk = u - cp * RWID;
        const int c  = cp * 2;
        int col = rbase + kk;
        if (col < 0)    col += W_;
        if (col >= W_)  col -= W_;
        const float a = Rrow[(size_t)c     * H_ * W_ + col];
        const float q = Rrow[(size_t)(c+1) * H_ * W_ + col];
        const unsigned int val =
            (unsigned int)f2b(a) | ((unsigned int)f2b(q) << 16);
        Rw[(kk * 64 + (c ^ ((kk & 7) << 3))) >> 1] = val;
    }
    __syncthreads();

    // ---- MFMA phase: wave wv owns 16-wide w1 tile [w0+16wv, +16) ----
    const int lane = tid & 63;
    const int wv   = tid >> 6;          // 0..3
    const int n15  = lane & 15;
    const int lg   = lane >> 4;         // 0..3

    // A-frags: L[w1][c], lane: w1 = 16wv + n15, c = lg*8 + j (+32)
    short8 afrag[2];
    {
        const int w = 16 * wv + n15;
#pragma unroll
        for (int q = 0; q < 2; ++q) {
            const int c = lg * 8 + 32 * q;
            afrag[q] = *(const short8*)&Lb[w * 64 + (c ^ ((w & 7) << 3))];
        }
    }

    float4v acc[NDL];
#pragma unroll
    for (int dl = 0; dl < NDL; ++dl) acc[dl] = (float4v)0.f;

#pragma unroll
    for (int dl = 0; dl < NDL; ++dl) {
        // B-frag tile start within Rb
        const int rlo = (S == 1) ? (96 + 16 * (wv - dl)) : (16 * (wv + dl));
        const int k   = rlo + n15;      // lane's w2-local index
#pragma unroll
        for (int q = 0; q < 2; ++q) {
            const int c = lg * 8 + 32 * q;
            const short8 bfrag = *(const short8*)&Rb[k * 64 + (c ^ ((k & 7) << 3))];
            acc[dl] = __builtin_amdgcn_mfma_f32_16x16x32_bf16(afrag[q], bfrag, acc[dl], 0, 0, 0);
        }
    }

    // ---- scatter MFMA tiles into Gs[w_local][d] ----
    // D layout (16x16x32): n = lane&15, m = (lane>>4)*4 + reg
#pragma unroll
    for (int dl = 0; dl < NDL; ++dl) {
#pragma unroll
        for (int r = 0; r < 4; ++r) {
            const int m = lg * 4 + r;
            const int d = (S == 1) ? (16 * dl + m - n15) : (16 * dl + n15 - m);
            if (0 <= d && d < D_)
                Gs[(16 * wv + m) * 97 + d] = acc[dl][r];
        }
    }
    __syncthreads();

    // ---- coalesced output: out[d][w0 .. w0+63] = Gs[.][d] ----
    const int w4 = tid & 15;
    const int dg = tid >> 4;
    float* obase = out + ((size_t)b * D_ * H_ + h) * W_ + w0 + w4 * 4;
#pragma unroll
    for (int p = 0; p < 6; ++p) {
        const int d = dg + 16 * p;
        float4 v;
        v.x = Gs[(w4 * 4 + 0) * 97 + d];
        v.y = Gs[(w4 * 4 + 1) * 97 + d];
        v.z = Gs[(w4 * 4 + 2) * 97 + d];
        v.w = Gs[(w4 * 4 + 3) * 97 + d];
        *(float4*)(obase + (size_t)d * H_ * W_) = v;
    }
}

extern "C" void kernel_launch(void* const* d_in, const int* in_sizes, int n_in,
                              void* d_out, int out_size, void* d_ws, size_t ws_size,
                              hipStream_t stream)
{
    const float* un_l = (const float*)d_in[0];
    const float* un_r = (const float*)d_in[1];
    const int*   dirp = (const int*)d_in[2];
    float* out = (float*)d_out;

    const int nwg = (W_ / TWB) * B_ * H_;   // 10 * 768 = 7680
    dim3 grid(nwg);
    dim3 block(256);

    // direction only known on device: launch both, mismatching one exits
    cost_volume_mfma<1><<<grid, block, 0, stream>>>(un_l, un_r, dirp, out);
    cost_volume_mfma<-1><<<grid, block, 0, stream>>>(un_l, un_r, dirp, out);
}

// Round 5
// 99.550 us; speedup vs baseline: 1.8503x; 1.0894x over previous
//
#include <hip/hip_runtime.h>

// Problem constants
#define B_   4
#define C_   64
#define H_   192
#define W_   640
#define D_   96     // disparities
#define TWB  64     // w1 columns per block
#define RWID 160    // staged R columns
#define NDL  7      // 16-wide delta tiles covering d in [0,96)
#define HW_  (H_ * W_)
#define GP   68     // Gs pitch (floats), mult of 4, non-pow2

typedef __attribute__((ext_vector_type(8))) short short8;
typedef __attribute__((ext_vector_type(4))) float float4v;

// bank swizzle: injects k bits 0..5 into the 8x16B slot index of a 128B row
#define SWZ(x) ((((x) ^ ((x) >> 3)) & 7) << 3)

// f32 -> bf16 round-to-nearest-even, packed pair
__device__ inline unsigned short f2b(float f) {
    unsigned int u = __builtin_bit_cast(unsigned int, f);
    u += 0x7FFFu + ((u >> 16) & 1u);
    return (unsigned short)(u >> 16);
}
__device__ inline unsigned int pk2(float lo, float hi) {
    return (unsigned int)f2b(lo) | ((unsigned int)f2b(hi) << 16);
}

// out[b,0,d,h,w] = sum_c L[b,c,h,w] * R[b,c,h,(w - d*S) mod W] = G[w][w - S*d]
template <int S>
__global__ __launch_bounds__(256)
void cost_volume_mfma(const float* __restrict__ Lp,
                      const float* __restrict__ Rp,
                      const int* __restrict__ dirp,
                      float* __restrict__ out)
{
    if (dirp[0] != S) return;   // self-select direction instantiation

    // 28672 B union:
    //   staging: Lb [64][64] u16 @ byte 0     (8 KB)
    //            Rb [160][64] u16 @ byte 8192 (20 KB)
    //   then reused as Gs [96][GP] f32 (26112 B)
    __shared__ unsigned int smem[7168];
    unsigned int* Lw = smem;                        // u32 view of Lb (word base 0)
    unsigned int* Rw = smem + 2048;                 // u32 view of Rb (byte 8192)
    const unsigned short* Lb = (const unsigned short*)smem;         // byte 0
    const unsigned short* Rb = (const unsigned short*)smem + 4096;  // byte 8192
    float* Gs = (float*)smem;

    // XCD-chunked bijective swizzle: nwg = 7680 = 8 * 960
    const int orig = blockIdx.x;
    const int nid  = (orig & 7) * 960 + (orig >> 3);
    const int bh   = nid / 10;
    const int t1g  = nid % 10;
    const int b  = bh / H_;
    const int h  = bh % H_;
    const int w0 = t1g * TWB;
    const int rbase = (S == 1) ? (w0 - 96) : w0;   // global col of Rb k=0

    const int tid = threadIdx.x;
    const float* Lrow = Lp + ((size_t)b * C_ * H_ + h) * W_;
    const float* Rrow = Rp + ((size_t)b * C_ * H_ + h) * W_;

    // ---- stage L: 32 cpair x 16 w4 = 512 units, 2/thread ----
#pragma unroll
    for (int u0 = 0; u0 < 2; ++u0) {
        const int u  = tid + u0 * 256;
        const int w4 = u & 15;
        const int c  = (u >> 4) * 2;
        const float* p0 = Lrow + (size_t)c * HW_ + w0 + 4 * w4;
        const float4 a = *(const float4*)p0;
        const float4 q = *(const float4*)(p0 + HW_);
        const float av[4] = {a.x, a.y, a.z, a.w};
        const float qv[4] = {q.x, q.y, q.z, q.w};
#pragma unroll
        for (int j = 0; j < 4; ++j) {
            const int w = 4 * w4 + j;
            Lw[w * 32 + ((c ^ SWZ(w)) >> 1)] = pk2(av[j], qv[j]);
        }
    }

    // ---- stage R: 32 cpair x 40 k4 = 1280 units, 5/thread ----
    {
        const int k8 = tid & 7;          // k4 low bits (coalescing)
        const int c  = (tid >> 3) * 2;   // channel pair (bank spread)
        const float* pc = Rrow + (size_t)c * HW_;
#pragma unroll
        for (int u0 = 0; u0 < 5; ++u0) {
            const int k4 = k8 + 8 * u0;
            int col = rbase + 4 * k4;    // float4 never straddles wrap (all mult of 4)
            if (col < 0)    col += W_;
            if (col >= W_)  col -= W_;
            const float4 a = *(const float4*)(pc + col);
            const float4 q = *(const float4*)(pc + HW_ + col);
            const float av[4] = {a.x, a.y, a.z, a.w};
            const float qv[4] = {q.x, q.y, q.z, q.w};
#pragma unroll
            for (int j = 0; j < 4; ++j) {
                const int k = 4 * k4 + j;
                Rw[k * 32 + ((c ^ SWZ(k)) >> 1)] = pk2(av[j], qv[j]);
            }
        }
    }
    __syncthreads();

    // ---- MFMA: wave wv owns w1 tile [w0+16wv, +16), 7 delta tiles x K=64 ----
    const int lane = tid & 63;
    const int wv   = tid >> 6;
    const int n15  = lane & 15;
    const int lg   = lane >> 4;

    short8 afrag[2];
    {
        const int w = 16 * wv + n15;
#pragma unroll
        for (int q = 0; q < 2; ++q) {
            const int c = lg * 8 + 32 * q;
            afrag[q] = *(const short8*)&Lb[w * 64 + (c ^ SWZ(w))];
        }
    }

    float4v acc[NDL];
#pragma unroll
    for (int dl = 0; dl < NDL; ++dl) acc[dl] = (float4v)0.f;

#pragma unroll
    for (int dl = 0; dl < NDL; ++dl) {
        const int rlo = (S == 1) ? (96 + 16 * (wv - dl)) : (16 * (wv + dl));
        const int k   = rlo + n15;
#pragma unroll
        for (int q = 0; q < 2; ++q) {
            const int c = lg * 8 + 32 * q;
            const short8 bfrag = *(const short8*)&Rb[k * 64 + (c ^ SWZ(k))];
            acc[dl] = __builtin_amdgcn_mfma_f32_16x16x32_bf16(afrag[q], bfrag, acc[dl], 0, 0, 0);
        }
    }
    __syncthreads();   // staging buffers dead; safe to overwrite with Gs

    // ---- scatter into Gs[d][w_local] (pitch 68) ----
    // D layout (16x16x32): n = lane&15 (w2), m = (lane>>4)*4 + reg (w1)
#pragma unroll
    for (int dl = 0; dl < NDL; ++dl) {
#pragma unroll
        for (int r = 0; r < 4; ++r) {
            const int m = lg * 4 + r;
            const int d = (S == 1) ? (16 * dl + m - n15) : (16 * dl + n15 - m);
            if (0 <= d && d < D_)
                Gs[d * GP + 16 * wv + m] = acc[dl][r];
        }
    }
    __syncthreads();

    // ---- coalesced epilogue: float4 LDS reads, float4 global stores ----
    const int w4 = tid & 15;
    const int dg = tid >> 4;
#pragma unroll
    for (int p = 0; p < 6; ++p) {
        const int d = dg + 16 * p;
        const float4 v = *(const float4*)&Gs[d * GP + 4 * w4];
        *(float4*)(out + ((size_t)(b * D_ + d) * H_ + h) * W_ + w0 + 4 * w4) = v;
    }
}

extern "C" void kernel_launch(void* const* d_in, const int* in_sizes, int n_in,
                              void* d_out, int out_size, void* d_ws, size_t ws_size,
                              hipStream_t stream)
{
    const float* un_l = (const float*)d_in[0];
    const float* un_r = (const float*)d_in[1];
    const int*   dirp = (const int*)d_in[2];
    float* out = (float*)d_out;

    const int nwg = (W_ / TWB) * B_ * H_;   // 7680
    dim3 grid(nwg);
    dim3 block(256);

    // direction only known on device: launch both, mismatching one exits
    cost_volume_mfma<1><<<grid, block, 0, stream>>>(un_l, un_r, dirp, out);
    cost_volume_mfma<-1><<<grid, block, 0, stream>>>(un_l, un_r, dirp, out);
}